// Round 11
// baseline (290.171 us; speedup 1.0000x reference)
//
#include <hip/hip_runtime.h>
#include <math.h>

#define SEQ_LEN   720
#define IN_LEN    360
#define PRED_LEN  336
#define CHANNELS  862
#define RANK      32
#define BATCH     256

typedef _Float16 h2 __attribute__((ext_vector_type(2)));

// ws float offsets
#define WS_WP    0        // Wp  [360][32] fp32
#define WS_VT    11520    // Vt  [336][32] fp32
#define WS_CVEC  22272    // cvec[336] fp32
#define WS_WH    22608    // packed W: u32[180*32]  word[np*32+r] = (W[2np][r], W[2np+1][r])
#define WS_VH    28368    // packed V: u32[336*16]  word[n*16+j]  = (V[n][2j],  V[n][2j+1])

__device__ __forceinline__ float fdot2w(h2 a, h2 b, float c) {
#if __has_builtin(__builtin_amdgcn_fdot2)
    return __builtin_amdgcn_fdot2(a, b, c, false);
#else
    return fmaf((float)a[0], (float)b[0], fmaf((float)a[1], (float)b[1], c));
#endif
}
__device__ __forceinline__ h2 pkrtz(float a, float b) {
    return __builtin_bit_cast(h2, __builtin_amdgcn_cvt_pkrtz(a, b));
}
#define BC(u) __builtin_bit_cast(h2, (u))

// ---------------- prep: fold DCT/IDCT into Wp, Vt, cvec ----------------------
__global__ __launch_bounds__(256) void k_prep(const float* __restrict__ A,
                                              const float* __restrict__ B,
                                              const float* __restrict__ bias,
                                              float* __restrict__ Wp,
                                              float* __restrict__ Vt,
                                              float* __restrict__ cvec) {
    __shared__ float sbuf[IN_LEN * RANK];
    int blk = blockIdx.x;
    if (blk < 45) {
        for (int i = threadIdx.x; i < IN_LEN * RANK; i += 256) sbuf[i] = A[i];
        __syncthreads();
        int idx = blk * 256 + threadIdx.x;           // 45*256 == 11520
        int n = idx >> 5, r = idx & 31;
        int step = 2 * n + 1, m = 0;                 // k*(2n+1) mod 1440
        float sum = 0.f;
        for (int k = 0; k < IN_LEN; ++k) {
            float coef = (k == 0) ? 0.05270462766947299f    // 1/sqrt(360)
                                  : 0.07453559924999299f;   // 2/sqrt(720)
            float d = coef * cospif((float)m * (1.0f / 720.0f));
            sum = fmaf(d, sbuf[k * RANK + r], sum);
            m += step; if (m >= 1440) m -= 1440;
        }
        Wp[idx] = sum * 0.0019641855032960957f;      // (1/sqrt2)/360
    } else if (blk < 87) {
        for (int i = threadIdx.x; i < PRED_LEN * RANK; i += 256) {
            int r = i / PRED_LEN, k = i - r * PRED_LEN;
            sbuf[k * RANK + r] = B[i];               // B^T -> [k][r]
        }
        __syncthreads();
        int idx = (blk - 45) * 256 + threadIdx.x;    // 42*256 == 10752
        int n = idx >> 5, r = idx & 31;
        int step = 2 * n + 1, m = 0;                 // k*(2n+1) mod 1344
        float sum = 0.f;
        for (int k = 0; k < PRED_LEN; ++k) {
            float mk = cospif((float)m * (1.0f / 672.0f));
            if (k == 0) mk *= 0.5f;
            sum = fmaf(mk, sbuf[k * RANK + r], sum);
            m += step; if (m >= 1344) m -= 1344;
        }
        Vt[idx] = sum * (1.0f / 336.0f);
    } else {
        int n = (blk - 87) * 256 + threadIdx.x;
        if (n < PRED_LEN) {
            int step = 2 * n + 1, m = 0;
            float sum = 0.f;
            for (int k = 0; k < PRED_LEN; ++k) {
                float mk = cospif((float)m * (1.0f / 672.0f));
                if (k == 0) mk *= 0.5f;
                sum = fmaf(mk, bias[k], sum);
                m += step; if (m >= 1344) m -= 1344;
            }
            cvec[n] = sum * (1.0f / 336.0f);
        }
    }
}

// ---------------- pack fp32 weights into paired fp16 -------------------------
// W n-paired (for phase-1 fdot2 over consecutive n); V r-paired (for phase 2).
__global__ __launch_bounds__(256) void k_pack(const float* __restrict__ Wp,
                                              const float* __restrict__ Vt,
                                              unsigned* __restrict__ Wh,
                                              unsigned* __restrict__ Vh) {
    int idx = blockIdx.x * 256 + threadIdx.x;        // 44*256 = 11264 >= 11136
    if (idx < 5760) {                                // 180*32
        int np = idx >> 5, r = idx & 31;
        h2 v = pkrtz(Wp[(2 * np) * RANK + r], Wp[(2 * np + 1) * RANK + r]);
        Wh[idx] = __builtin_bit_cast(unsigned, v);
    } else if (idx < 5760 + 5376) {                  // 336*16
        int j = idx - 5760;
        int n = j >> 4, q = j & 15;
        h2 v = pkrtz(Vt[n * RANK + 2 * q], Vt[n * RANK + 2 * q + 1]);
        Vh[j] = __builtin_bit_cast(unsigned, v);
    }
}

// ---------------- fused main kernel ------------------------------------------
// 448-thr block (431 active, 96% lanes), one block per batch, grid 256.
// cpt=2, full 720 rows per thread -> no k-split, no exchange, ONE barrier.
// W(23K)+V(21.5K)+cvec staged together (45.9 KB LDS). Full-row contiguous
// sweeps on both streams. fp16-paired weights, fdot2, fp32 acc + mean path.
__global__ __launch_bounds__(448) void k_main(const float* __restrict__ x,
                                              const float* __restrict__ A,
                                              const unsigned* __restrict__ Wh,
                                              const unsigned* __restrict__ Vh,
                                              const float* __restrict__ cvec,
                                              float* __restrict__ out) {
    __shared__ uint4 lds4[2868];                     // 45888 B: W 0..1439, V 1440..2783, cvec tail
    unsigned* ldsu = (unsigned*)lds4;
    const int tid = threadIdx.x;
    const int b = blockIdx.x;
    const int c0 = 2 * tid;
    const bool active = (tid < 431);                 // 431*2 == 862 exactly

    // ---- stage W, V, cvec (single staging, single barrier) ----
    for (int i = tid; i < 1440; i += 448) lds4[i] = ((const uint4*)Wh)[i];
    for (int i = tid; i < 1344; i += 448) lds4[1440 + i] = ((const uint4*)Vh)[i];
    for (int i = tid; i < PRED_LEN; i += 448) ldsu[11136 + i] = __float_as_uint(cvec[i]);
    __syncthreads();

    float acc0[RANK], acc1[RANK];
    #pragma unroll
    for (int r = 0; r < RANK; ++r) { acc0[r] = 0.f; acc1[r] = 0.f; }
    float S0 = 0.f, S1 = 0.f, mean0 = 0.f, mean1 = 0.f;
    h2 th0[16], th1[16];

    if (active) {
        const float* xp = x + (size_t)b * (SEQ_LEN * CHANNELS) + c0;

        // chunk bd = 8 x-rows = 4 n = 2 np; 90 chunks cover 720 rows
        float2 bufA[8], bufB[8];
        #define LOADB(BUF, BD) { const float* p_ = xp + (size_t)(BD) * (8 * CHANNELS); \
            _Pragma("unroll") \
            for (int j_ = 0; j_ < 8; ++j_) BUF[j_] = *(const float2*)(p_ + j_ * CHANNELS); }

        // one n-pair: rows BUF[4S..4S+3]; W words at wr[8S..8S+7]
        #define NPBODY(BUF, S_) { \
            float pe0 = BUF[4*S_+0].x + BUF[4*S_+1].x; \
            float pe1 = BUF[4*S_+0].y + BUF[4*S_+1].y; \
            float po0 = BUF[4*S_+2].x + BUF[4*S_+3].x; \
            float po1 = BUF[4*S_+2].y + BUF[4*S_+3].y; \
            S0 += pe0 + po0; S1 += pe1 + po1; \
            h2 P0 = pkrtz(pe0, po0); \
            h2 P1 = pkrtz(pe1, po1); \
            _Pragma("unroll") \
            for (int q_ = 0; q_ < 8; ++q_) { \
                uint4 wv = wr[8*S_ + q_]; \
                acc0[4*q_+0] = fdot2w(P0, BC(wv.x), acc0[4*q_+0]); \
                acc1[4*q_+0] = fdot2w(P1, BC(wv.x), acc1[4*q_+0]); \
                acc0[4*q_+1] = fdot2w(P0, BC(wv.y), acc0[4*q_+1]); \
                acc1[4*q_+1] = fdot2w(P1, BC(wv.y), acc1[4*q_+1]); \
                acc0[4*q_+2] = fdot2w(P0, BC(wv.z), acc0[4*q_+2]); \
                acc1[4*q_+2] = fdot2w(P1, BC(wv.z), acc1[4*q_+2]); \
                acc0[4*q_+3] = fdot2w(P0, BC(wv.w), acc0[4*q_+3]); \
                acc1[4*q_+3] = fdot2w(P1, BC(wv.w), acc1[4*q_+3]); \
            } }

        #define BODY(BUF, BD) { const uint4* wr = lds4 + 16 * (BD); \
            NPBODY(BUF, 0); NPBODY(BUF, 1); }

        LOADB(bufA, 0)
        for (int it = 0; it < 45; ++it) {            // 45 iters x 2 chunks = 90 chunks
            LOADB(bufB, 2 * it + 1)
            BODY(bufA, 2 * it)
            if (it < 44) LOADB(bufA, 2 * it + 2)
            BODY(bufB, 2 * it + 1)
        }
        #undef BODY
        #undef NPBODY
        #undef LOADB

        // finalize: csw[r] = A[0][r]/sqrt(720);  t -= (S/360)*csw  (fp32 exact)
        const float k360 = (1.0f / 360.0f) * 0.037267799624996496f;
        float g0 = -S0 * k360, g1 = -S1 * k360;
        #pragma unroll
        for (int q = 0; q < 8; ++q) {
            float4 a4 = ((const float4*)A)[q];       // A[0][0..31], uniform, L2-hot
            acc0[4*q+0] = fmaf(g0, a4.x, acc0[4*q+0]);
            acc1[4*q+0] = fmaf(g1, a4.x, acc1[4*q+0]);
            acc0[4*q+1] = fmaf(g0, a4.y, acc0[4*q+1]);
            acc1[4*q+1] = fmaf(g1, a4.y, acc1[4*q+1]);
            acc0[4*q+2] = fmaf(g0, a4.z, acc0[4*q+2]);
            acc1[4*q+2] = fmaf(g1, a4.z, acc1[4*q+2]);
            acc0[4*q+3] = fmaf(g0, a4.w, acc0[4*q+3]);
            acc1[4*q+3] = fmaf(g1, a4.w, acc1[4*q+3]);
        }
        mean0 = S0 * (1.0f / 720.0f);
        mean1 = S1 * (1.0f / 720.0f);

        // pack t to fp16 r-pairs for phase 2
        #pragma unroll
        for (int u = 0; u < 16; ++u) {
            th0[u] = pkrtz(acc0[2*u], acc0[2*u+1]);
            th1[u] = pkrtz(acc1[2*u], acc1[2*u+1]);
        }

        // ---- phase 2: out[b][n][c] = t . V[n][:] + cvec[n] + mean ----
        float* op = out + (size_t)b * (PRED_LEN * CHANNELS) + c0;
        #pragma unroll 2
        for (int n = 0; n < PRED_LEN; ++n) {
            const uint4* vr = lds4 + 1440 + n * 4;
            float oA0 = 0.f, oB0 = 0.f, oA1 = 0.f, oB1 = 0.f;
            #pragma unroll
            for (int q = 0; q < 4; ++q) {
                uint4 v = vr[q];
                oA0 = fdot2w(th0[4*q+0], BC(v.x), oA0);
                oA1 = fdot2w(th1[4*q+0], BC(v.x), oA1);
                oB0 = fdot2w(th0[4*q+1], BC(v.y), oB0);
                oB1 = fdot2w(th1[4*q+1], BC(v.y), oB1);
                oA0 = fdot2w(th0[4*q+2], BC(v.z), oA0);
                oA1 = fdot2w(th1[4*q+2], BC(v.z), oA1);
                oB0 = fdot2w(th0[4*q+3], BC(v.w), oB0);
                oB1 = fdot2w(th1[4*q+3], BC(v.w), oB1);
            }
            float cvn = __uint_as_float(ldsu[11136 + n]);
            float2 o;
            o.x = (oA0 + oB0) + cvn + mean0;
            o.y = (oA1 + oB1) + cvn + mean1;
            *(float2*)op = o;
            op += CHANNELS;
        }
    }
}

// ---------------- launcher ---------------------------------------------------

extern "C" void kernel_launch(void* const* d_in, const int* in_sizes, int n_in,
                              void* d_out, int out_size, void* d_ws, size_t ws_size,
                              hipStream_t stream) {
    (void)in_sizes; (void)n_in; (void)out_size; (void)ws_size;
    const float* x    = (const float*)d_in[0];
    const float* A    = (const float*)d_in[1];
    const float* B    = (const float*)d_in[2];
    const float* bias = (const float*)d_in[3];
    float* out = (float*)d_out;
    float* ws  = (float*)d_ws;

    float*    Wp   = ws + WS_WP;
    float*    Vt   = ws + WS_VT;
    float*    cvec = ws + WS_CVEC;
    unsigned* Wh   = (unsigned*)(ws + WS_WH);
    unsigned* Vh   = (unsigned*)(ws + WS_VH);

    k_prep<<<dim3(89), dim3(256), 0, stream>>>(A, B, bias, Wp, Vt, cvec);
    k_pack<<<dim3(44), dim3(256), 0, stream>>>(Wp, Vt, Wh, Vh);
    k_main<<<dim3(BATCH), dim3(448), 0, stream>>>(x, A, Wh, Vh, cvec, out);
}